// Round 11
// baseline (1276.090 us; speedup 1.0000x reference)
//
#include <hip/hip_runtime.h>

#define COL_DIM 4096
#define ROW_DIM 1024
#define NUM_LAYERS 3
#define KNN_E 16384
#define GENET_E 131072

typedef __attribute__((ext_vector_type(8))) short short8;
typedef __attribute__((ext_vector_type(4))) float f32x4;

// ---------------- fp32 -> bf16 hi/lo helpers ----------------
__device__ inline unsigned short f2bf(float f) {
  unsigned int u = __float_as_uint(f);
  u += 0x7FFFu + ((u >> 16) & 1u); // RNE
  return (unsigned short)(u >> 16);
}
__device__ inline float bf2f(unsigned short h) {
  return __uint_as_float(((unsigned int)h) << 16);
}

// ---------------- transpose + split: in[R][C] -> outf/outh/outl [C][R] --------
__global__ void transpose_split_kernel(const float* __restrict__ in,
                                       float* __restrict__ outf,
                                       unsigned short* __restrict__ outh,
                                       unsigned short* __restrict__ outl,
                                       int R, int C) {
  __shared__ float tile[32][33];
  int c0 = blockIdx.x * 32, r0 = blockIdx.y * 32;
  int tx = threadIdx.x, ty = threadIdx.y; // 32 x 8
#pragma unroll
  for (int i = 0; i < 32; i += 8)
    tile[ty + i][tx] = in[(size_t)(r0 + ty + i) * C + c0 + tx];
  __syncthreads();
#pragma unroll
  for (int i = 0; i < 32; i += 8) {
    float v = tile[tx][ty + i];
    size_t o = (size_t)(c0 + ty + i) * R + r0 + tx;
    outf[o] = v;
    unsigned short h = f2bf(v);
    outh[o] = h;
    outl[o] = f2bf(v - bf2f(h));
  }
}

// ---------------- CSR build ----------------
__global__ void count_kernel(const int* __restrict__ dst, int E, int* __restrict__ cnt) {
  int e = blockIdx.x * 256 + threadIdx.x;
  if (e < E) atomicAdd(&cnt[dst[e]], 1);
}

__global__ void scan_kernel(const int* __restrict__ cnt, int* __restrict__ indptr, int n) {
  __shared__ int s[1024];
  __shared__ int base_s;
  int tid = threadIdx.x;
  if (tid == 0) { base_s = 0; indptr[0] = 0; }
  __syncthreads();
  for (int c = 0; c < n; c += 1024) {
    int i = c + tid;
    int v = (i < n) ? cnt[i] : 0;
    s[tid] = v;
    __syncthreads();
    for (int off = 1; off < 1024; off <<= 1) {
      int t = (tid >= off) ? s[tid - off] : 0;
      __syncthreads();
      s[tid] += t;
      __syncthreads();
    }
    if (i < n) indptr[i + 1] = base_s + s[tid];
    __syncthreads();
    if (tid == 0) base_s += s[1023];
    __syncthreads();
  }
}

__global__ void copy_int_kernel(const int* __restrict__ a, int* __restrict__ b, int n) {
  int i = blockIdx.x * 256 + threadIdx.x;
  if (i < n) b[i] = a[i];
}

__global__ void fill_kernel(const int* __restrict__ src, const int* __restrict__ dst, int E,
                            int* __restrict__ cursor, int* __restrict__ idx) {
  int e = blockIdx.x * 256 + threadIdx.x;
  if (e < E) {
    int p = atomicAdd(&cursor[dst[e]], 1);
    idx[p] = src[e];
  }
}

// ---------------- wave-per-bucket rank sort (deterministic: sorted by value) ---
__global__ void rank_sort_kernel(const int* __restrict__ indptr, int* __restrict__ idx,
                                 int n) {
  int wv = threadIdx.x >> 6, lane = threadIdx.x & 63;
  int b = blockIdx.x * (blockDim.x >> 6) + wv;
  if (b >= n) return;
  int lo = indptr[b];
  int d = indptr[b + 1] - lo;
  if (d <= 1) return;
  if (d <= 256) {
    int v0 = (lane < d) ? idx[lo + lane] : 0x7fffffff;
    int v1 = (64 + lane < d) ? idx[lo + 64 + lane] : 0x7fffffff;
    int v2 = (128 + lane < d) ? idx[lo + 128 + lane] : 0x7fffffff;
    int v3 = (192 + lane < d) ? idx[lo + 192 + lane] : 0x7fffffff;
    int r0 = 0, r1 = 0, r2 = 0, r3 = 0;
    for (int j = 0; j < d; j++) {
      int q = j >> 6;
      int sel = (q == 0) ? v0 : (q == 1) ? v1 : (q == 2) ? v2 : v3;
      int bj = __shfl(sel, j & 63);
      r0 += (bj < v0 || (bj == v0 && j < lane)) ? 1 : 0;
      r1 += (bj < v1 || (bj == v1 && j < 64 + lane)) ? 1 : 0;
      r2 += (bj < v2 || (bj == v2 && j < 128 + lane)) ? 1 : 0;
      r3 += (bj < v3 || (bj == v3 && j < 192 + lane)) ? 1 : 0;
    }
    if (lane < d) idx[lo + r0] = v0;
    if (64 + lane < d) idx[lo + r1] = v1;
    if (128 + lane < d) idx[lo + r2] = v2;
    if (192 + lane < d) idx[lo + r3] = v3;
  } else if (lane == 0) {
    for (int i = lo + 1; i < lo + d; i++) {
      int v = idx[i];
      int j = i - 1;
      while (j >= lo && idx[j] > v) { idx[j + 1] = idx[j]; j--; }
      idx[j + 1] = v;
    }
  }
}

// ---------------- neighbor mean, XCD-sliced, + split to bf16 hi/lo ------------
__global__ void agg_slice_kernel(const float* __restrict__ src,
                                 unsigned short* __restrict__ dh,
                                 unsigned short* __restrict__ dl,
                                 const int* __restrict__ indptr,
                                 const int* __restrict__ idx, int D, int tprsh) {
  int tid = threadIdx.x;
  int d = blockIdx.y * (256 >> tprsh) + (tid >> tprsh);
  int k4 = blockIdx.x * (1 << tprsh) + (tid & ((1 << tprsh) - 1));
  int lo = indptr[d], hi = indptr[d + 1];
  float4 s = make_float4(0.f, 0.f, 0.f, 0.f);
  for (int j = lo; j < hi; j++) {
    float4 v = ((const float4*)(src + (size_t)idx[j] * D))[k4];
    s.x += v.x; s.y += v.y; s.z += v.z; s.w += v.w;
  }
  int c = hi - lo;
  float inv = 1.f / (float)(c > 0 ? c : 1);
  s.x *= inv; s.y *= inv; s.z *= inv; s.w *= inv;
  ushort4 h, l;
  h.x = f2bf(s.x); l.x = f2bf(s.x - bf2f(h.x));
  h.y = f2bf(s.y); l.y = f2bf(s.y - bf2f(h.y));
  h.z = f2bf(s.z); l.z = f2bf(s.z - bf2f(h.z));
  h.w = f2bf(s.w); l.w = f2bf(s.w - bf2f(h.w));
  ((ushort4*)(dh + (size_t)d * D))[k4] = h;
  ((ushort4*)(dl + (size_t)d * D))[k4] = l;
}

// ---------------- plain split for weights ----------------
__global__ void split_kernel(const float* __restrict__ src, unsigned short* __restrict__ dh,
                             unsigned short* __restrict__ dl, int n4) {
  int i = blockIdx.x * 256 + threadIdx.x;
  int stride = gridDim.x * 256;
  for (; i < n4; i += stride) {
    float4 v = ((const float4*)src)[i];
    ushort4 h, l;
    h.x = f2bf(v.x); l.x = f2bf(v.x - bf2f(h.x));
    h.y = f2bf(v.y); l.y = f2bf(v.y - bf2f(h.y));
    h.z = f2bf(v.z); l.z = f2bf(v.z - bf2f(h.z));
    h.w = f2bf(v.w); l.w = f2bf(v.w - bf2f(h.w));
    ((ushort4*)dh)[i] = h;
    ((ushort4*)dl)[i] = l;
  }
}

// ---------------- virtual-K phase-pipelined bf16 NT GEMM (BK=64) ----------------
// 6 virtual segments of KA each. 256x256 tile, 8 waves, wave tile 128x64.
// LDS sm[2 buf][2 op][2 khalf][256*32] = 128KB; rows of 32 bf16 (64B).
// Per K-tile (64): 2 phases. Phase kh: {12 ds_read of khalf kh; lgkmcnt(0);
// barrier (region's readers ALL done); stage khalf kh of tile t+2 into SAME
// buffer (disjoint-by-construction: sub-buffer); setprio + 32 MFMA}.
// Tile boundary: vmcnt(8) (t+2's 8 GLDS newest; all older done => t+1 landed)
// + barrier. Swizzle: physical 16B-slot p of row r holds logical p^((r>>1)&3)
// (r10-verified: 2-way, free).
#define GLDS(g, l)                                                             \
  __builtin_amdgcn_global_load_lds(                                            \
      (const __attribute__((address_space(1))) void*)(g),                      \
      (__attribute__((address_space(3))) void*)(l), 16, 0, 0)

#define BAR()                                                                  \
  {                                                                            \
    asm volatile("" ::: "memory");                                             \
    __builtin_amdgcn_s_barrier();                                              \
    asm volatile("" ::: "memory");                                             \
  }

#define SEGA(si) ((si)==0?A0s:(si)==1?A1s:(si)==2?A2s:(si)==3?A3s:(si)==4?A4s:A5s)
#define SEGB(si) ((si)==0?B0s:(si)==1?B1s:(si)==2?B2s:(si)==3?B3s:(si)==4?B4s:B5s)

// stage khalf kh of virtual tile vt into buffer buf (2 GLDS each; 4 per phase)
#define STAGE_A(vt, kh, buf)                                                   \
  {                                                                            \
    int si_ = (vt) >> segshift;                                                \
    size_t ko_ = (size_t)((vt) & segmask) * 64 + (kh) * 32;                    \
    const unsigned short* As_ = SEGA(si_);                                     \
    GLDS(As_ + gA0 + ko_, &sm[buf][0][kh][tid * 8]);                           \
    GLDS(As_ + gA0 + (size_t)128 * KA + ko_, &sm[buf][0][kh][tid * 8 + 4096]); \
  }
#define STAGE_B(vt, kh, buf)                                                   \
  {                                                                            \
    int si_ = (vt) >> segshift;                                                \
    size_t ko_ = (size_t)((vt) & segmask) * 64 + (kh) * 32;                    \
    const unsigned short* Bs_ = SEGB(si_);                                     \
    GLDS(Bs_ + gB0 + ko_, &sm[buf][1][kh][tid * 8]);                           \
    GLDS(Bs_ + gB0 + (size_t)128 * KA + ko_, &sm[buf][1][kh][tid * 8 + 4096]); \
  }

__global__ __launch_bounds__(512, 2) void vk_gemm_kernel(
    const unsigned short* __restrict__ A0s, const unsigned short* __restrict__ A1s,
    const unsigned short* __restrict__ A2s, const unsigned short* __restrict__ A3s,
    const unsigned short* __restrict__ A4s, const unsigned short* __restrict__ A5s,
    const unsigned short* __restrict__ B0s, const unsigned short* __restrict__ B1s,
    const unsigned short* __restrict__ B2s, const unsigned short* __restrict__ B3s,
    const unsigned short* __restrict__ B4s, const unsigned short* __restrict__ B5s,
    float* __restrict__ P0, float* __restrict__ P1,
    float* __restrict__ P2, float* __restrict__ P3,
    int KA, int segshift, int tpb) {
  __shared__ unsigned short sm[2][2][2][8192]; // buf x {A,B} x khalf x 256rows*32k
  const int tid = threadIdx.x;
  const int lane = tid & 63;
  const int wid = tid >> 6;              // 8 waves
  const int wm = wid >> 2, wn = wid & 3; // wave tile: rows wm*128.., cols wn*64..

  const int bid = blockIdx.x;                  // 256 blocks
  const int swz = (bid & 7) * 32 + (bid >> 3); // XCD-chunked
  const int sk = swz >> 6;                     // splitK 0..3
  const int tile = swz & 63;                   // 16 m-tiles x 4 n-tiles
  const int bm0 = (tile >> 2) * 256;
  const int bn0 = (tile & 3) * 256;
  const int vt0 = sk * tpb;
  const int segmask = (1 << segshift) - 1;

  // staging: per (op, khalf) 1024 units of 16B; thread handles u=tid, tid+512.
  // r0 = tid>>2 in [0,128); u+512 -> row+128, same slot XOR (128>>1 % 4 == 0).
  const int r0 = tid >> 2;
  const int q0 = (tid & 3) ^ ((r0 >> 1) & 3);
  const size_t gA0 = (size_t)(bm0 + r0) * KA + q0 * 8;
  const size_t gB0 = (size_t)(bn0 + r0) * KA + q0 * 8;

  // ds_read: logical k-slot s=lane>>4 at row lr -> physical s^((lr>>1)&3);
  // frag-row steps (16,64,128) are 0 mod 4 after >>1 -> constant per thread.
  const int xsl = ((lane >> 4) ^ (((lane & 15) >> 1) & 3)) * 8;
  const int offA = (wm * 128 + (lane & 15)) * 32 + xsl; // +i*512 per frag
  const int offB = (wn * 64 + (lane & 15)) * 32 + xsl;  // +j*512 per frag

  f32x4 acc[8][4];
#pragma unroll
  for (int i = 0; i < 8; i++)
#pragma unroll
    for (int j = 0; j < 4; j++) acc[i][j] = (f32x4)(0.f);

  // prologue: tiles vt0, vt0+1 into bufs 0,1 (8 GLDS each); tpb >= 24 always
  STAGE_A(vt0 + 0, 0, 0); STAGE_A(vt0 + 0, 1, 0);
  STAGE_B(vt0 + 0, 0, 0); STAGE_B(vt0 + 0, 1, 0);
  STAGE_A(vt0 + 1, 0, 1); STAGE_A(vt0 + 1, 1, 1);
  STAGE_B(vt0 + 1, 0, 1); STAGE_B(vt0 + 1, 1, 1);
  asm volatile("s_waitcnt vmcnt(8)" ::: "memory"); // tile 0's 8 landed
  BAR();

#pragma unroll 1
  for (int t = 0; t < tpb; ++t) {
    const int b = t & 1;
    short8 av[8], bv[4];
#pragma unroll
    for (int kh = 0; kh < 2; ++kh) {
      const unsigned short* smA = &sm[b][0][kh][0];
      const unsigned short* smB = &sm[b][1][kh][0];
#pragma unroll
      for (int i = 0; i < 8; i++) av[i] = *(const short8*)(smA + offA + i * 512);
#pragma unroll
      for (int j = 0; j < 4; j++) bv[j] = *(const short8*)(smB + offB + j * 512);
      asm volatile("s_waitcnt lgkmcnt(0)" ::: "memory"); // my khalf reads done
      BAR(); // ALL waves' reads of this khalf region done -> region free
      if (t + 2 < tpb) {
        STAGE_A(vt0 + t + 2, kh, b); // same buffer, freed sub-region
        STAGE_B(vt0 + t + 2, kh, b);
      }
      __builtin_amdgcn_s_setprio(1);
#pragma unroll
      for (int i = 0; i < 8; i++)
#pragma unroll
        for (int j = 0; j < 4; j++)
          acc[i][j] = __builtin_amdgcn_mfma_f32_16x16x32_bf16(av[i], bv[j],
                                                              acc[i][j], 0, 0, 0);
      __builtin_amdgcn_s_setprio(0);
    }
    // boundary: tile t+1 must be fully landed before next iteration reads it
    if (t + 1 < tpb) {
      if (t + 2 < tpb) {
        asm volatile("s_waitcnt vmcnt(8)" ::: "memory"); // only t+2's 8 newest
      } else {
        asm volatile("s_waitcnt vmcnt(0)" ::: "memory");
      }
      BAR();
    }
  }

  float* P = sk == 0 ? P0 : sk == 1 ? P1 : sk == 2 ? P2 : P3;
  const int rq = (lane >> 4) * 4;
  const int cq = lane & 15;
#pragma unroll
  for (int i = 0; i < 8; i++) {
#pragma unroll
    for (int j = 0; j < 4; j++) {
#pragma unroll
      for (int e = 0; e < 4; e++) {
        int row = bm0 + wm * 128 + i * 16 + rq + e;
        int col = bn0 + wn * 64 + j * 16 + cq;
        P[(size_t)row * 1024 + col] = acc[i][j][e];
      }
    }
  }
}

// ---------------- combine4: C = leaky(P0..P3 + bias[row]) + hi/lo split --------
__global__ void combine_split_kernel(const float* __restrict__ P0, const float* __restrict__ P1,
                                     const float* __restrict__ P2, const float* __restrict__ P3,
                                     const float* __restrict__ bias, float* __restrict__ Cf,
                                     unsigned short* __restrict__ Ch,
                                     unsigned short* __restrict__ Cl) {
  int i = blockIdx.x * 256 + threadIdx.x; // float4 index, 1M total
  float4 a = ((const float4*)P0)[i];
  float4 b = ((const float4*)P1)[i];
  float4 c = ((const float4*)P2)[i];
  float4 d = ((const float4*)P3)[i];
  float bb = bias[(i * 4) >> 10];
  float4 v;
  v.x = a.x + b.x + c.x + d.x + bb;
  v.y = a.y + b.y + c.y + d.y + bb;
  v.z = a.z + b.z + c.z + d.z + bb;
  v.w = a.w + b.w + c.w + d.w + bb;
  v.x = v.x > 0.f ? v.x : 0.01f * v.x;
  v.y = v.y > 0.f ? v.y : 0.01f * v.y;
  v.z = v.z > 0.f ? v.z : 0.01f * v.z;
  v.w = v.w > 0.f ? v.w : 0.01f * v.w;
  ((float4*)Cf)[i] = v;
  ushort4 h, l;
  h.x = f2bf(v.x); l.x = f2bf(v.x - bf2f(h.x));
  h.y = f2bf(v.y); l.y = f2bf(v.y - bf2f(h.y));
  h.z = f2bf(v.z); l.z = f2bf(v.z - bf2f(h.z));
  h.w = f2bf(v.w); l.w = f2bf(v.w - bf2f(h.w));
  ((ushort4*)Ch)[i] = h;
  ((ushort4*)Cl)[i] = l;
}

// ---------------- combine4: C = leaky(P0..P3 + bias[col]) ----------------
__global__ void combine_kernel(const float* __restrict__ P0, const float* __restrict__ P1,
                               const float* __restrict__ P2, const float* __restrict__ P3,
                               const float* __restrict__ bias, float* __restrict__ C) {
  int i = blockIdx.x * 256 + threadIdx.x;
  float4 a = ((const float4*)P0)[i];
  float4 b = ((const float4*)P1)[i];
  float4 c = ((const float4*)P2)[i];
  float4 d = ((const float4*)P3)[i];
  float4 bb = *(const float4*)(bias + ((i * 4) & 1023));
  float4 v;
  v.x = a.x + b.x + c.x + d.x + bb.x;
  v.y = a.y + b.y + c.y + d.y + bb.y;
  v.z = a.z + b.z + c.z + d.z + bb.z;
  v.w = a.w + b.w + c.w + d.w + bb.w;
  v.x = v.x > 0.f ? v.x : 0.01f * v.x;
  v.y = v.y > 0.f ? v.y : 0.01f * v.y;
  v.z = v.z > 0.f ? v.z : 0.01f * v.z;
  v.w = v.w > 0.f ? v.w : 0.01f * v.w;
  ((float4*)C)[i] = v;
}

extern "C" void kernel_launch(void* const* d_in, const int* in_sizes, int n_in,
                              void* d_out, int out_size, void* d_ws, size_t ws_size,
                              hipStream_t stream) {
  const float* x      = (const float*)d_in[0];
  const float* col_Wl = (const float*)d_in[1];
  const float* col_Wr = (const float*)d_in[2];
  const float* col_b  = (const float*)d_in[3];
  const float* row_Wl = (const float*)d_in[4];
  const float* row_Wr = (const float*)d_in[5];
  const float* row_b  = (const float*)d_in[6];
  const int*   knn    = (const int*)d_in[7];   // [2][KNN_E]
  const int*   genet  = (const int*)d_in[8];   // [2][GENET_E]
  float* out = (float*)d_out;

  const size_t MAT = (size_t)COL_DIM * ROW_DIM; // 4M elements
  const size_t WCOL = (size_t)COL_DIM * COL_DIM; // 16M
  const size_t WROW = (size_t)ROW_DIM * ROW_DIM; // 1M
  char* w = (char*)d_ws;
  float* X1f = (float*)w; w += MAT * 4;                 // ET then E1 (fp32)
  unsigned short* X2h = (unsigned short*)w; w += MAT * 2; // ETh/l then E1h/l
  unsigned short* X2l = (unsigned short*)w; w += MAT * 2;
  unsigned short* X3h = (unsigned short*)w; w += MAT * 2; // Mh/l then Gh/l
  unsigned short* X3l = (unsigned short*)w; w += MAT * 2;
  unsigned short* WLh = (unsigned short*)w; w += WCOL * 2; // 32MB
  unsigned short* WLl = (unsigned short*)w; w += WCOL * 2;
  unsigned short* WRh = (unsigned short*)w; w += WCOL * 2;
  unsigned short* WRl = (unsigned short*)w; w += WCOL * 2;
  unsigned short* RLh = (unsigned short*)w; w += WROW * 2; // 2MB
  unsigned short* RLl = (unsigned short*)w; w += WROW * 2;
  unsigned short* RRh = (unsigned short*)w; w += WROW * 2;
  unsigned short* RRl = (unsigned short*)w; w += WROW * 2;
  float* PP0 = (float*)w; w += MAT * 4;
  float* PP1 = (float*)w; w += MAT * 4;
  float* PP2 = (float*)w; w += MAT * 4;
  float* PP3 = (float*)w; w += MAT * 4;
  int* kcnt = (int*)w; w += 1024 * 4;
  int* kptr = (int*)w; w += 1025 * 4;
  int* kidx = (int*)w; w += KNN_E * 4;
  int* gcnt = (int*)w; w += 4096 * 4;
  int* gptr = (int*)w; w += 4097 * 4;
  int* gidx = (int*)w; w += (size_t)GENET_E * 4;

  // ---- CSR build (deterministic via per-bucket value sort) ----
  hipMemsetAsync(kcnt, 0, 1024 * 4, stream);
  hipMemsetAsync(gcnt, 0, 4096 * 4, stream);
  count_kernel<<<KNN_E / 256, 256, 0, stream>>>(knn + KNN_E, KNN_E, kcnt);
  count_kernel<<<GENET_E / 256, 256, 0, stream>>>(genet + GENET_E, GENET_E, gcnt);
  scan_kernel<<<1, 1024, 0, stream>>>(kcnt, kptr, 1024);
  scan_kernel<<<1, 1024, 0, stream>>>(gcnt, gptr, 4096);
  copy_int_kernel<<<4, 256, 0, stream>>>(kptr, kcnt, 1024);
  copy_int_kernel<<<16, 256, 0, stream>>>(gptr, gcnt, 4096);
  fill_kernel<<<KNN_E / 256, 256, 0, stream>>>(knn, knn + KNN_E, KNN_E, kcnt, kidx);
  fill_kernel<<<GENET_E / 256, 256, 0, stream>>>(genet, genet + GENET_E, GENET_E, gcnt, gidx);
  rank_sort_kernel<<<256, 256, 0, stream>>>(kptr, kidx, 1024);
  rank_sort_kernel<<<1024, 256, 0, stream>>>(gptr, gidx, 4096);

  const float* Ein = x;
  for (int i = 0; i < NUM_LAYERS; i++) {
    const float* cWl = col_Wl + (size_t)i * WCOL;
    const float* cWr = col_Wr + (size_t)i * WCOL;
    const float* cb  = col_b + (size_t)i * COL_DIM;
    const float* rWl = row_Wl + (size_t)i * WROW;
    const float* rWr = row_Wr + (size_t)i * WROW;
    const float* rb  = row_b + (size_t)i * ROW_DIM;

    // ---- column branch: E1 = leaky(cWl@M^T + cWr@ET^T + cb[row]) ----
    transpose_split_kernel<<<dim3(ROW_DIM / 32, COL_DIM / 32), dim3(32, 8), 0, stream>>>(
        Ein, X1f, X2h, X2l, COL_DIM, ROW_DIM);
    agg_slice_kernel<<<dim3(8, 512), 256, 0, stream>>>(X1f, X3h, X3l, kptr, kidx,
                                                       COL_DIM, 7);
    split_kernel<<<2048, 256, 0, stream>>>(cWl, WLh, WLl, (int)(WCOL / 4));
    split_kernel<<<2048, 256, 0, stream>>>(cWr, WRh, WRl, (int)(WCOL / 4));
    // segments: (WLh,Mh)(WLh,Ml)(WLl,Mh) (WRh,ETh)(WRh,ETl)(WRl,ETh)
    // KA=4096 -> 64 vtiles/seg -> segshift=6; total 384 vtiles -> tpb=96
    vk_gemm_kernel<<<256, 512, 0, stream>>>(
        WLh, WLh, WLl, WRh, WRh, WRl,
        X3h, X3l, X3h, X2h, X2l, X2h,
        PP0, PP1, PP2, PP3, COL_DIM, 6, 96);
    combine_split_kernel<<<4096, 256, 0, stream>>>(PP0, PP1, PP2, PP3, cb,
                                                   X1f, X2h, X2l); // E1 f32+h/l
    // ---- row branch: out = leaky(G@rWl^T + E1@rWr^T + rb[col]) ----
    agg_slice_kernel<<<dim3(8, 512), 256, 0, stream>>>(X1f, X3h, X3l, gptr, gidx,
                                                       ROW_DIM, 5);
    split_kernel<<<1024, 256, 0, stream>>>(rWl, RLh, RLl, (int)(WROW / 4));
    split_kernel<<<1024, 256, 0, stream>>>(rWr, RRh, RRl, (int)(WROW / 4));
    // KA=1024 -> 16 vtiles/seg -> segshift=4; total 96 vtiles -> tpb=24
    vk_gemm_kernel<<<256, 512, 0, stream>>>(
        X3h, X3h, X3l, X2h, X2h, X2l,
        RLh, RLl, RLh, RRh, RRl, RRh,
        PP0, PP1, PP2, PP3, ROW_DIM, 4, 24);
    combine_kernel<<<4096, 256, 0, stream>>>(PP0, PP1, PP2, PP3, rb, out);

    Ein = out;
  }
}

// Round 12
// 1252.969 us; speedup vs baseline: 1.0185x; 1.0185x over previous
//
#include <hip/hip_runtime.h>

#define COL_DIM 4096
#define ROW_DIM 1024
#define NUM_LAYERS 3
#define KNN_E 16384
#define GENET_E 131072

typedef __attribute__((ext_vector_type(8))) short short8;
typedef __attribute__((ext_vector_type(4))) float f32x4;

// ---------------- fp32 -> bf16 hi/lo helpers ----------------
__device__ inline unsigned short f2bf(float f) {
  unsigned int u = __float_as_uint(f);
  u += 0x7FFFu + ((u >> 16) & 1u); // RNE
  return (unsigned short)(u >> 16);
}
__device__ inline float bf2f(unsigned short h) {
  return __uint_as_float(((unsigned int)h) << 16);
}

// ---------------- transpose + split: in[R][C] -> outf/outh/outl [C][R] --------
__global__ void transpose_split_kernel(const float* __restrict__ in,
                                       float* __restrict__ outf,
                                       unsigned short* __restrict__ outh,
                                       unsigned short* __restrict__ outl,
                                       int R, int C) {
  __shared__ float tile[32][33];
  int c0 = blockIdx.x * 32, r0 = blockIdx.y * 32;
  int tx = threadIdx.x, ty = threadIdx.y; // 32 x 8
#pragma unroll
  for (int i = 0; i < 32; i += 8)
    tile[ty + i][tx] = in[(size_t)(r0 + ty + i) * C + c0 + tx];
  __syncthreads();
#pragma unroll
  for (int i = 0; i < 32; i += 8) {
    float v = tile[tx][ty + i];
    size_t o = (size_t)(c0 + ty + i) * R + r0 + tx;
    outf[o] = v;
    unsigned short h = f2bf(v);
    outh[o] = h;
    outl[o] = f2bf(v - bf2f(h));
  }
}

// ---------------- CSR build ----------------
__global__ void count_kernel(const int* __restrict__ dst, int E, int* __restrict__ cnt) {
  int e = blockIdx.x * 256 + threadIdx.x;
  if (e < E) atomicAdd(&cnt[dst[e]], 1);
}

__global__ void scan_kernel(const int* __restrict__ cnt, int* __restrict__ indptr, int n) {
  __shared__ int s[1024];
  __shared__ int base_s;
  int tid = threadIdx.x;
  if (tid == 0) { base_s = 0; indptr[0] = 0; }
  __syncthreads();
  for (int c = 0; c < n; c += 1024) {
    int i = c + tid;
    int v = (i < n) ? cnt[i] : 0;
    s[tid] = v;
    __syncthreads();
    for (int off = 1; off < 1024; off <<= 1) {
      int t = (tid >= off) ? s[tid - off] : 0;
      __syncthreads();
      s[tid] += t;
      __syncthreads();
    }
    if (i < n) indptr[i + 1] = base_s + s[tid];
    __syncthreads();
    if (tid == 0) base_s += s[1023];
    __syncthreads();
  }
}

__global__ void copy_int_kernel(const int* __restrict__ a, int* __restrict__ b, int n) {
  int i = blockIdx.x * 256 + threadIdx.x;
  if (i < n) b[i] = a[i];
}

__global__ void fill_kernel(const int* __restrict__ src, const int* __restrict__ dst, int E,
                            int* __restrict__ cursor, int* __restrict__ idx) {
  int e = blockIdx.x * 256 + threadIdx.x;
  if (e < E) {
    int p = atomicAdd(&cursor[dst[e]], 1);
    idx[p] = src[e];
  }
}

// ---------------- wave-per-bucket rank sort (deterministic: sorted by value) ---
__global__ void rank_sort_kernel(const int* __restrict__ indptr, int* __restrict__ idx,
                                 int n) {
  int wv = threadIdx.x >> 6, lane = threadIdx.x & 63;
  int b = blockIdx.x * (blockDim.x >> 6) + wv;
  if (b >= n) return;
  int lo = indptr[b];
  int d = indptr[b + 1] - lo;
  if (d <= 1) return;
  if (d <= 256) {
    int v0 = (lane < d) ? idx[lo + lane] : 0x7fffffff;
    int v1 = (64 + lane < d) ? idx[lo + 64 + lane] : 0x7fffffff;
    int v2 = (128 + lane < d) ? idx[lo + 128 + lane] : 0x7fffffff;
    int v3 = (192 + lane < d) ? idx[lo + 192 + lane] : 0x7fffffff;
    int r0 = 0, r1 = 0, r2 = 0, r3 = 0;
    for (int j = 0; j < d; j++) {
      int q = j >> 6;
      int sel = (q == 0) ? v0 : (q == 1) ? v1 : (q == 2) ? v2 : v3;
      int bj = __shfl(sel, j & 63);
      r0 += (bj < v0 || (bj == v0 && j < lane)) ? 1 : 0;
      r1 += (bj < v1 || (bj == v1 && j < 64 + lane)) ? 1 : 0;
      r2 += (bj < v2 || (bj == v2 && j < 128 + lane)) ? 1 : 0;
      r3 += (bj < v3 || (bj == v3 && j < 192 + lane)) ? 1 : 0;
    }
    if (lane < d) idx[lo + r0] = v0;
    if (64 + lane < d) idx[lo + r1] = v1;
    if (128 + lane < d) idx[lo + r2] = v2;
    if (192 + lane < d) idx[lo + r3] = v3;
  } else if (lane == 0) {
    for (int i = lo + 1; i < lo + d; i++) {
      int v = idx[i];
      int j = i - 1;
      while (j >= lo && idx[j] > v) { idx[j + 1] = idx[j]; j--; }
      idx[j + 1] = v;
    }
  }
}

// ---------------- neighbor mean, XCD-sliced, + split to bf16 hi/lo ------------
__global__ void agg_slice_kernel(const float* __restrict__ src,
                                 unsigned short* __restrict__ dh,
                                 unsigned short* __restrict__ dl,
                                 const int* __restrict__ indptr,
                                 const int* __restrict__ idx, int D, int tprsh) {
  int tid = threadIdx.x;
  int d = blockIdx.y * (256 >> tprsh) + (tid >> tprsh);
  int k4 = blockIdx.x * (1 << tprsh) + (tid & ((1 << tprsh) - 1));
  int lo = indptr[d], hi = indptr[d + 1];
  float4 s = make_float4(0.f, 0.f, 0.f, 0.f);
  for (int j = lo; j < hi; j++) {
    float4 v = ((const float4*)(src + (size_t)idx[j] * D))[k4];
    s.x += v.x; s.y += v.y; s.z += v.z; s.w += v.w;
  }
  int c = hi - lo;
  float inv = 1.f / (float)(c > 0 ? c : 1);
  s.x *= inv; s.y *= inv; s.z *= inv; s.w *= inv;
  ushort4 h, l;
  h.x = f2bf(s.x); l.x = f2bf(s.x - bf2f(h.x));
  h.y = f2bf(s.y); l.y = f2bf(s.y - bf2f(h.y));
  h.z = f2bf(s.z); l.z = f2bf(s.z - bf2f(h.z));
  h.w = f2bf(s.w); l.w = f2bf(s.w - bf2f(h.w));
  ((ushort4*)(dh + (size_t)d * D))[k4] = h;
  ((ushort4*)(dl + (size_t)d * D))[k4] = l;
}

// ---------------- plain split for weights ----------------
__global__ void split_kernel(const float* __restrict__ src, unsigned short* __restrict__ dh,
                             unsigned short* __restrict__ dl, int n4) {
  int i = blockIdx.x * 256 + threadIdx.x;
  int stride = gridDim.x * 256;
  for (; i < n4; i += stride) {
    float4 v = ((const float4*)src)[i];
    ushort4 h, l;
    h.x = f2bf(v.x); l.x = f2bf(v.x - bf2f(h.x));
    h.y = f2bf(v.y); l.y = f2bf(v.y - bf2f(h.y));
    h.z = f2bf(v.z); l.z = f2bf(v.z - bf2f(h.z));
    h.w = f2bf(v.w); l.w = f2bf(v.w - bf2f(h.w));
    ((ushort4*)dh)[i] = h;
    ((ushort4*)dl)[i] = l;
  }
}

// ---------------- virtual-K 8-phase pipelined bf16 NT GEMM (m201 template) -----
// 6 virtual segments of KA each. 256x256 tile, BK=64, 8 waves, wave tile 128x64.
// LDS: 2 dbuf x 4 regions {A0,A1,B0,B1} x (128 rows x 64 ushorts) = 128KB.
// Iter = 2 K-tiles (d0 at phases 0-3, d1 at 4-7). Phase = {4-8 ds_read;
// 1 region-stage (2 GLDS); BAR; lgkmcnt(0); setprio+16 MFMA; BAR}.
// Stage rotation: ph0:B1d1<-tp+1 ph1:A0d1<-tp+1 ph2:A1d1<-tp+1 ph3:B0d0<-tp+2
// ph4:B1d0<-tp+2 ph5:A0d0<-tp+2 ph6:A1d0<-tp+2 ph7:B0d1<-tp+3.
// Ledger: each stage >=1 phase after its region's last reader retires (B-regions
// of d0 free after ph2, A after ph3; d1: ph6/ph7). vmcnt(2) before the closing
// barrier of ph3/ph7 makes every region land >=1 phase before its first read
// (tail: vmcnt degrades to 0 when the allowed-in-flight stage is guarded off).
// Swizzle: 8 slots/row, physical slot p holds logical p^(r&7): 16-lane column
// reads cover all 8 bank-quads twice -> 2-way, free.
#define GLDS(g, l)                                                             \
  __builtin_amdgcn_global_load_lds(                                            \
      (const __attribute__((address_space(1))) void*)(g),                      \
      (__attribute__((address_space(3))) void*)(l), 16, 0, 0)

#define BAR()                                                                  \
  {                                                                            \
    asm volatile("" ::: "memory");                                             \
    __builtin_amdgcn_s_barrier();                                              \
    asm volatile("" ::: "memory");                                             \
  }

#define SEGA(si) ((si)==0?A0s:(si)==1?A1s:(si)==2?A2s:(si)==3?A3s:(si)==4?A4s:A5s)
#define SEGB(si) ((si)==0?B0s:(si)==1?B1s:(si)==2?B2s:(si)==3?B3s:(si)==4?B4s:B5s)

__global__ __launch_bounds__(512, 1) void vk_gemm_kernel(
    const unsigned short* __restrict__ A0s, const unsigned short* __restrict__ A1s,
    const unsigned short* __restrict__ A2s, const unsigned short* __restrict__ A3s,
    const unsigned short* __restrict__ A4s, const unsigned short* __restrict__ A5s,
    const unsigned short* __restrict__ B0s, const unsigned short* __restrict__ B1s,
    const unsigned short* __restrict__ B2s, const unsigned short* __restrict__ B3s,
    const unsigned short* __restrict__ B4s, const unsigned short* __restrict__ B5s,
    float* __restrict__ P0, float* __restrict__ P1,
    float* __restrict__ P2, float* __restrict__ P3,
    int KA, int segshift, int tpb) {
  __shared__ __align__(16) unsigned short sm[2][4][8192]; // [d][A0,A1,B0,B1][128x64]
  const int tid = threadIdx.x;
  const int lane = tid & 63;
  const int wid = tid >> 6;              // 8 waves
  const int wm = wid >> 2, wn = wid & 3; // wave tile: rows wm*128.., cols wn*64..

  const int bid = blockIdx.x;                  // 256 blocks
  const int swz = (bid & 7) * 32 + (bid >> 3); // XCD-chunked
  const int sk = swz >> 6;                     // splitK 0..3
  const int tile = swz & 63;                   // 16 m-tiles x 4 n-tiles
  const int bm0 = (tile >> 2) * 256;
  const int bn0 = (tile & 3) * 256;
  const int vt0 = sk * tpb;
  const int segmask = (1 << segshift) - 1;

  // staging geometry: region = 128 rows x 8 slots of 16B = 1024 units;
  // thread: u0=tid (rows 0-63), u1=tid+512 (rows 64-127, same slot & XOR).
  const int rl = tid >> 3;
  const size_t koff = (size_t)(((tid & 7) ^ (rl & 7)) * 8);

  // ds_read offsets (ushorts within a region): row lr -> lr*64; slot for
  // kslice s: ((4s + (lane>>4)) ^ (lane&7)) * 8  (lr&7 == lane&7, frag-invariant)
  const int off0 = (((lane >> 4) ^ (lane & 7)) * 8);
  const int off1 = (((4 + (lane >> 4)) ^ (lane & 7)) * 8);
  const int aBase = wm * 2 * 8192 * 0 + wm * 8192 + (lane & 15) * 64; // region A_wm
  const int bBase = (2 + (wn >> 1)) * 8192 + ((wn & 1) * 64 + (lane & 15)) * 64;

  f32x4 acc[8][4];
#pragma unroll
  for (int i = 0; i < 8; i++)
#pragma unroll
    for (int j = 0; j < 4; j++) acc[i][j] = (f32x4)(0.f);

  // stage one region (2 GLDS) of local virtual tile vt into sm[d][reg]
  auto STG = [&](int vtl, int d, int reg) {
    if (vtl < tpb) {
      int vt = vt0 + vtl;
      int si = vt >> segshift;
      size_t ko = (size_t)(vt & segmask) * 64 + koff;
      const unsigned short* S = (reg < 2) ? SEGA(si) : SEGB(si);
      size_t rowbase = (reg == 0) ? (size_t)bm0 : (reg == 1) ? (size_t)bm0 + 128
                       : (reg == 2) ? (size_t)bn0 : (size_t)bn0 + 128;
      const unsigned short* src = S + (rowbase + rl) * KA + ko;
      GLDS(src, &sm[d][reg][tid * 8]);
      GLDS(src + (size_t)64 * KA, &sm[d][reg][tid * 8 + 4096]);
    }
  };

  short8 av[4], bv[4];
  const unsigned short* smd;

#define RDB(soff) {                                                            \
    _Pragma("unroll") for (int j = 0; j < 4; j++)                              \
      bv[j] = *(const short8*)(smd + bBase + j * 1024 + (soff)); }
#define RDA(q, soff) {                                                         \
    _Pragma("unroll") for (int ii = 0; ii < 4; ii++)                           \
      av[ii] = *(const short8*)(smd + aBase + ((q) * 4 + ii) * 1024 + (soff)); }
#define MM(q) {                                                                \
    __builtin_amdgcn_s_setprio(1);                                             \
    _Pragma("unroll") for (int ii = 0; ii < 4; ii++)                           \
      _Pragma("unroll") for (int j = 0; j < 4; j++)                            \
        acc[(q) * 4 + ii][j] = __builtin_amdgcn_mfma_f32_16x16x32_bf16(        \
            av[ii], bv[j], acc[(q) * 4 + ii][j], 0, 0, 0);                     \
    __builtin_amdgcn_s_setprio(0); }
#define LGKM() asm volatile("s_waitcnt lgkmcnt(0)" ::: "memory")

  // prologue: tile0 all regions (d0) + tile1's B0 (d1)
  STG(0, 0, 2); STG(0, 0, 3); STG(0, 0, 0); STG(0, 0, 1);
  STG(1, 1, 2);
  asm volatile("s_waitcnt vmcnt(2)" ::: "memory"); // tile0 landed; B0d1 may fly
  BAR();

  const int iters = tpb >> 1;
#pragma unroll 1
  for (int it = 0; it < iters; ++it) {
    const int tp = 2 * it;
    // ---- K-tile tp (d0) ----
    smd = &sm[0][0][0];
    // ph0
    RDB(off0); RDA(0, off0); STG(tp + 1, 1, 3);
    BAR(); LGKM(); MM(0); BAR();
    // ph1
    RDA(1, off0); STG(tp + 1, 1, 0);
    BAR(); LGKM(); MM(1); BAR();
    // ph2
    RDB(off1); RDA(0, off1); STG(tp + 1, 1, 1);
    BAR(); LGKM(); MM(0); BAR();
    // ph3 (+vmcnt: d1-tile tp+1 fully landed, allow ph3's own stage in flight)
    RDA(1, off1); STG(tp + 2, 0, 2);
    BAR(); LGKM(); MM(1);
    if (tp + 2 < tpb) { asm volatile("s_waitcnt vmcnt(2)" ::: "memory"); }
    else              { asm volatile("s_waitcnt vmcnt(0)" ::: "memory"); }
    BAR();
    // ---- K-tile tp+1 (d1) ----
    smd = &sm[1][0][0];
    // ph4
    RDB(off0); RDA(0, off0); STG(tp + 2, 0, 3);
    BAR(); LGKM(); MM(0); BAR();
    // ph5
    RDA(1, off0); STG(tp + 2, 0, 0);
    BAR(); LGKM(); MM(1); BAR();
    // ph6
    RDB(off1); RDA(0, off1); STG(tp + 2, 0, 1);
    BAR(); LGKM(); MM(0); BAR();
    // ph7 (+vmcnt: d0-tile tp+2 fully landed, allow ph7's own stage in flight)
    RDA(1, off1); STG(tp + 3, 1, 2);
    BAR(); LGKM(); MM(1);
    if (tp + 3 < tpb) { asm volatile("s_waitcnt vmcnt(2)" ::: "memory"); }
    else              { asm volatile("s_waitcnt vmcnt(0)" ::: "memory"); }
    BAR();
  }

  float* P = sk == 0 ? P0 : sk == 1 ? P1 : sk == 2 ? P2 : P3;
  const int rq = (lane >> 4) * 4;
  const int cq = lane & 15;
#pragma unroll
  for (int i = 0; i < 8; i++) {
#pragma unroll
    for (int j = 0; j < 4; j++) {
#pragma unroll
      for (int e = 0; e < 4; e++) {
        int row = bm0 + wm * 128 + i * 16 + rq + e;
        int col = bn0 + wn * 64 + j * 16 + cq;
        P[(size_t)row * 1024 + col] = acc[i][j][e];
      }
    }
  }
}

// ---------------- combine4: C = leaky(P0..P3 + bias[row]) + hi/lo split --------
__global__ void combine_split_kernel(const float* __restrict__ P0, const float* __restrict__ P1,
                                     const float* __restrict__ P2, const float* __restrict__ P3,
                                     const float* __restrict__ bias, float* __restrict__ Cf,
                                     unsigned short* __restrict__ Ch,
                                     unsigned short* __restrict__ Cl) {
  int i = blockIdx.x * 256 + threadIdx.x; // float4 index, 1M total
  float4 a = ((const float4*)P0)[i];
  float4 b = ((const float4*)P1)[i];
  float4 c = ((const float4*)P2)[i];
  float4 d = ((const float4*)P3)[i];
  float bb = bias[(i * 4) >> 10];
  float4 v;
  v.x = a.x + b.x + c.x + d.x + bb;
  v.y = a.y + b.y + c.y + d.y + bb;
  v.z = a.z + b.z + c.z + d.z + bb;
  v.w = a.w + b.w + c.w + d.w + bb;
  v.x = v.x > 0.f ? v.x : 0.01f * v.x;
  v.y = v.y > 0.f ? v.y : 0.01f * v.y;
  v.z = v.z > 0.f ? v.z : 0.01f * v.z;
  v.w = v.w > 0.f ? v.w : 0.01f * v.w;
  ((float4*)Cf)[i] = v;
  ushort4 h, l;
  h.x = f2bf(v.x); l.x = f2bf(v.x - bf2f(h.x));
  h.y = f2bf(v.y); l.y = f2bf(v.y - bf2f(h.y));
  h.z = f2bf(v.z); l.z = f2bf(v.z - bf2f(h.z));
  h.w = f2bf(v.w); l.w = f2bf(v.w - bf2f(h.w));
  ((ushort4*)Ch)[i] = h;
  ((ushort4*)Cl)[i] = l;
}

// ---------------- combine4: C = leaky(P0..P3 + bias[col]) ----------------
__global__ void combine_kernel(const float* __restrict__ P0, const float* __restrict__ P1,
                               const float* __restrict__ P2, const float* __restrict__ P3,
                               const float* __restrict__ bias, float* __restrict__ C) {
  int i = blockIdx.x * 256 + threadIdx.x;
  float4 a = ((const float4*)P0)[i];
  float4 b = ((const float4*)P1)[i];
  float4 c = ((const float4*)P2)[i];
  float4 d = ((const float4*)P3)[i];
  float4 bb = *(const float4*)(bias + ((i * 4) & 1023));
  float4 v;
  v.x = a.x + b.x + c.x + d.x + bb.x;
  v.y = a.y + b.y + c.y + d.y + bb.y;
  v.z = a.z + b.z + c.z + d.z + bb.z;
  v.w = a.w + b.w + c.w + d.w + bb.w;
  v.x = v.x > 0.f ? v.x : 0.01f * v.x;
  v.y = v.y > 0.f ? v.y : 0.01f * v.y;
  v.z = v.z > 0.f ? v.z : 0.01f * v.z;
  v.w = v.w > 0.f ? v.w : 0.01f * v.w;
  ((float4*)C)[i] = v;
}

extern "C" void kernel_launch(void* const* d_in, const int* in_sizes, int n_in,
                              void* d_out, int out_size, void* d_ws, size_t ws_size,
                              hipStream_t stream) {
  const float* x      = (const float*)d_in[0];
  const float* col_Wl = (const float*)d_in[1];
  const float* col_Wr = (const float*)d_in[2];
  const float* col_b  = (const float*)d_in[3];
  const float* row_Wl = (const float*)d_in[4];
  const float* row_Wr = (const float*)d_in[5];
  const float* row_b  = (const float*)d_in[6];
  const int*   knn    = (const int*)d_in[7];   // [2][KNN_E]
  const int*   genet  = (const int*)d_in[8];   // [2][GENET_E]
  float* out = (float*)d_out;

  const size_t MAT = (size_t)COL_DIM * ROW_DIM; // 4M elements
  const size_t WCOL = (size_t)COL_DIM * COL_DIM; // 16M
  const size_t WROW = (size_t)ROW_DIM * ROW_DIM; // 1M
  char* w = (char*)d_ws;
  float* X1f = (float*)w; w += MAT * 4;                 // ET then E1 (fp32)
  unsigned short* X2h = (unsigned short*)w; w += MAT * 2; // ETh/l then E1h/l
  unsigned short* X2l = (unsigned short*)w; w += MAT * 2;
  unsigned short* X3h = (unsigned short*)w; w += MAT * 2; // Mh/l then Gh/l
  unsigned short* X3l = (unsigned short*)w; w += MAT * 2;
  unsigned short* WLh = (unsigned short*)w; w += WCOL * 2; // 32MB
  unsigned short* WLl = (unsigned short*)w; w += WCOL * 2;
  unsigned short* WRh = (unsigned short*)w; w += WCOL * 2;
  unsigned short* WRl = (unsigned short*)w; w += WCOL * 2;
  unsigned short* RLh = (unsigned short*)w; w += WROW * 2; // 2MB
  unsigned short* RLl = (unsigned short*)w; w += WROW * 2;
  unsigned short* RRh = (unsigned short*)w; w += WROW * 2;
  unsigned short* RRl = (unsigned short*)w; w += WROW * 2;
  float* PP0 = (float*)w; w += MAT * 4;
  float* PP1 = (float*)w; w += MAT * 4;
  float* PP2 = (float*)w; w += MAT * 4;
  float* PP3 = (float*)w; w += MAT * 4;
  int* kcnt = (int*)w; w += 1024 * 4;
  int* kptr = (int*)w; w += 1025 * 4;
  int* kidx = (int*)w; w += KNN_E * 4;
  int* gcnt = (int*)w; w += 4096 * 4;
  int* gptr = (int*)w; w += 4097 * 4;
  int* gidx = (int*)w; w += (size_t)GENET_E * 4;

  // ---- CSR build (deterministic via per-bucket value sort) ----
  hipMemsetAsync(kcnt, 0, 1024 * 4, stream);
  hipMemsetAsync(gcnt, 0, 4096 * 4, stream);
  count_kernel<<<KNN_E / 256, 256, 0, stream>>>(knn + KNN_E, KNN_E, kcnt);
  count_kernel<<<GENET_E / 256, 256, 0, stream>>>(genet + GENET_E, GENET_E, gcnt);
  scan_kernel<<<1, 1024, 0, stream>>>(kcnt, kptr, 1024);
  scan_kernel<<<1, 1024, 0, stream>>>(gcnt, gptr, 4096);
  copy_int_kernel<<<4, 256, 0, stream>>>(kptr, kcnt, 1024);
  copy_int_kernel<<<16, 256, 0, stream>>>(gptr, gcnt, 4096);
  fill_kernel<<<KNN_E / 256, 256, 0, stream>>>(knn, knn + KNN_E, KNN_E, kcnt, kidx);
  fill_kernel<<<GENET_E / 256, 256, 0, stream>>>(genet, genet + GENET_E, GENET_E, gcnt, gidx);
  rank_sort_kernel<<<256, 256, 0, stream>>>(kptr, kidx, 1024);
  rank_sort_kernel<<<1024, 256, 0, stream>>>(gptr, gidx, 4096);

  const float* Ein = x;
  for (int i = 0; i < NUM_LAYERS; i++) {
    const float* cWl = col_Wl + (size_t)i * WCOL;
    const float* cWr = col_Wr + (size_t)i * WCOL;
    const float* cb  = col_b + (size_t)i * COL_DIM;
    const float* rWl = row_Wl + (size_t)i * WROW;
    const float* rWr = row_Wr + (size_t)i * WROW;
    const float* rb  = row_b + (size_t)i * ROW_DIM;

    // ---- column branch: E1 = leaky(cWl@M^T + cWr@ET^T + cb[row]) ----
    transpose_split_kernel<<<dim3(ROW_DIM / 32, COL_DIM / 32), dim3(32, 8), 0, stream>>>(
        Ein, X1f, X2h, X2l, COL_DIM, ROW_DIM);
    agg_slice_kernel<<<dim3(8, 512), 256, 0, stream>>>(X1f, X3h, X3l, kptr, kidx,
                                                       COL_DIM, 7);
    split_kernel<<<2048, 256, 0, stream>>>(cWl, WLh, WLl, (int)(WCOL / 4));
    split_kernel<<<2048, 256, 0, stream>>>(cWr, WRh, WRl, (int)(WCOL / 4));
    // segments: (WLh,Mh)(WLh,Ml)(WLl,Mh) (WRh,ETh)(WRh,ETl)(WRl,ETh)
    // KA=4096 -> 64 BK64-tiles/seg -> segshift=6; 384 vtiles -> tpb=96
    vk_gemm_kernel<<<256, 512, 0, stream>>>(
        WLh, WLh, WLl, WRh, WRh, WRl,
        X3h, X3l, X3h, X2h, X2l, X2h,
        PP0, PP1, PP2, PP3, COL_DIM, 6, 96);
    combine_split_kernel<<<4096, 256, 0, stream>>>(PP0, PP1, PP2, PP3, cb,
                                                   X1f, X2h, X2l); // E1 f32+h/l
    // ---- row branch: out = leaky(G@rWl^T + E1@rWr^T + rb[col]) ----
    agg_slice_kernel<<<dim3(8, 512), 256, 0, stream>>>(X1f, X3h, X3l, gptr, gidx,
                                                       ROW_DIM, 5);
    split_kernel<<<1024, 256, 0, stream>>>(rWl, RLh, RLl, (int)(WROW / 4));
    split_kernel<<<1024, 256, 0, stream>>>(rWr, RRh, RRl, (int)(WROW / 4));
    // KA=1024 -> 16 tiles/seg -> segshift=4; 96 vtiles -> tpb=24
    vk_gemm_kernel<<<256, 512, 0, stream>>>(
        X3h, X3h, X3l, X2h, X2h, X2l,
        RLh, RLl, RLh, RRh, RRl, RRh,
        PP0, PP1, PP2, PP3, ROW_DIM, 4, 24);
    combine_kernel<<<4096, 256, 0, stream>>>(PP0, PP1, PP2, PP3, rb, out);

    Ein = out;
  }
}

// Round 13
// 1174.619 us; speedup vs baseline: 1.0864x; 1.0667x over previous
//
#include <hip/hip_runtime.h>

#define COL_DIM 4096
#define ROW_DIM 1024
#define NUM_LAYERS 3
#define KNN_E 16384
#define GENET_E 131072

typedef __attribute__((ext_vector_type(8))) short short8;
typedef __attribute__((ext_vector_type(4))) float f32x4;

// ---------------- fp32 -> bf16 hi/lo helpers ----------------
__device__ inline unsigned short f2bf(float f) {
  unsigned int u = __float_as_uint(f);
  u += 0x7FFFu + ((u >> 16) & 1u); // RNE
  return (unsigned short)(u >> 16);
}
__device__ inline float bf2f(unsigned short h) {
  return __uint_as_float(((unsigned int)h) << 16);
}
// packed HW convert: dst.lo16 = bf16(a), dst.hi16 = bf16(b)
__device__ inline unsigned int cvtpk(float a, float b) {
  unsigned int r;
  asm("v_cvt_pk_bf16_f32 %0, %1, %2" : "=v"(r) : "v"(a), "v"(b));
  return r;
}
// 8 floats -> hi short8 + lo short8. Self-correcting: lo from ACTUAL hi.
__device__ inline void cvt_f4pair(float4 a4, float4 b4, short8& h, short8& l) {
  float f[8] = {a4.x, a4.y, a4.z, a4.w, b4.x, b4.y, b4.z, b4.w};
  union { unsigned int u[4]; short8 s; } H, L;
#pragma unroll
  for (int w = 0; w < 4; w++) {
    float a = f[2 * w], b = f[2 * w + 1];
    unsigned int hw = cvtpk(a, b);
    float ah = __uint_as_float(hw << 16);
    float bh = __uint_as_float(hw & 0xffff0000u);
    H.u[w] = hw;
    L.u[w] = cvtpk(a - ah, b - bh);
  }
  h = H.s;
  l = L.s;
}

// ---------------- transpose + split: in[R][C] -> outf/outh/outl [C][R] --------
__global__ void transpose_split_kernel(const float* __restrict__ in,
                                       float* __restrict__ outf,
                                       unsigned short* __restrict__ outh,
                                       unsigned short* __restrict__ outl,
                                       int R, int C) {
  __shared__ float tile[32][33];
  int c0 = blockIdx.x * 32, r0 = blockIdx.y * 32;
  int tx = threadIdx.x, ty = threadIdx.y; // 32 x 8
#pragma unroll
  for (int i = 0; i < 32; i += 8)
    tile[ty + i][tx] = in[(size_t)(r0 + ty + i) * C + c0 + tx];
  __syncthreads();
#pragma unroll
  for (int i = 0; i < 32; i += 8) {
    float v = tile[tx][ty + i];
    size_t o = (size_t)(c0 + ty + i) * R + r0 + tx;
    outf[o] = v;
    unsigned short h = f2bf(v);
    outh[o] = h;
    outl[o] = f2bf(v - bf2f(h));
  }
}

// ---------------- CSR build ----------------
__global__ void count_kernel(const int* __restrict__ dst, int E, int* __restrict__ cnt) {
  int e = blockIdx.x * 256 + threadIdx.x;
  if (e < E) atomicAdd(&cnt[dst[e]], 1);
}

__global__ void scan_kernel(const int* __restrict__ cnt, int* __restrict__ indptr, int n) {
  __shared__ int s[1024];
  __shared__ int base_s;
  int tid = threadIdx.x;
  if (tid == 0) { base_s = 0; indptr[0] = 0; }
  __syncthreads();
  for (int c = 0; c < n; c += 1024) {
    int i = c + tid;
    int v = (i < n) ? cnt[i] : 0;
    s[tid] = v;
    __syncthreads();
    for (int off = 1; off < 1024; off <<= 1) {
      int t = (tid >= off) ? s[tid - off] : 0;
      __syncthreads();
      s[tid] += t;
      __syncthreads();
    }
    if (i < n) indptr[i + 1] = base_s + s[tid];
    __syncthreads();
    if (tid == 0) base_s += s[1023];
    __syncthreads();
  }
}

__global__ void copy_int_kernel(const int* __restrict__ a, int* __restrict__ b, int n) {
  int i = blockIdx.x * 256 + threadIdx.x;
  if (i < n) b[i] = a[i];
}

__global__ void fill_kernel(const int* __restrict__ src, const int* __restrict__ dst, int E,
                            int* __restrict__ cursor, int* __restrict__ idx) {
  int e = blockIdx.x * 256 + threadIdx.x;
  if (e < E) {
    int p = atomicAdd(&cursor[dst[e]], 1);
    idx[p] = src[e];
  }
}

// ---------------- wave-per-bucket rank sort (deterministic: sorted by value) ---
__global__ void rank_sort_kernel(const int* __restrict__ indptr, int* __restrict__ idx,
                                 int n) {
  int wv = threadIdx.x >> 6, lane = threadIdx.x & 63;
  int b = blockIdx.x * (blockDim.x >> 6) + wv;
  if (b >= n) return;
  int lo = indptr[b];
  int d = indptr[b + 1] - lo;
  if (d <= 1) return;
  if (d <= 256) {
    int v0 = (lane < d) ? idx[lo + lane] : 0x7fffffff;
    int v1 = (64 + lane < d) ? idx[lo + 64 + lane] : 0x7fffffff;
    int v2 = (128 + lane < d) ? idx[lo + 128 + lane] : 0x7fffffff;
    int v3 = (192 + lane < d) ? idx[lo + 192 + lane] : 0x7fffffff;
    int r0 = 0, r1 = 0, r2 = 0, r3 = 0;
    for (int j = 0; j < d; j++) {
      int q = j >> 6;
      int sel = (q == 0) ? v0 : (q == 1) ? v1 : (q == 2) ? v2 : v3;
      int bj = __shfl(sel, j & 63);
      r0 += (bj < v0 || (bj == v0 && j < lane)) ? 1 : 0;
      r1 += (bj < v1 || (bj == v1 && j < 64 + lane)) ? 1 : 0;
      r2 += (bj < v2 || (bj == v2 && j < 128 + lane)) ? 1 : 0;
      r3 += (bj < v3 || (bj == v3 && j < 192 + lane)) ? 1 : 0;
    }
    if (lane < d) idx[lo + r0] = v0;
    if (64 + lane < d) idx[lo + r1] = v1;
    if (128 + lane < d) idx[lo + r2] = v2;
    if (192 + lane < d) idx[lo + r3] = v3;
  } else if (lane == 0) {
    for (int i = lo + 1; i < lo + d; i++) {
      int v = idx[i];
      int j = i - 1;
      while (j >= lo && idx[j] > v) { idx[j + 1] = idx[j]; j--; }
      idx[j + 1] = v;
    }
  }
}

// ---------------- neighbor mean, XCD-sliced, + split to bf16 hi/lo ------------
__global__ void agg_slice_kernel(const float* __restrict__ src,
                                 unsigned short* __restrict__ dh,
                                 unsigned short* __restrict__ dl,
                                 const int* __restrict__ indptr,
                                 const int* __restrict__ idx, int D, int tprsh) {
  int tid = threadIdx.x;
  int d = blockIdx.y * (256 >> tprsh) + (tid >> tprsh);
  int k4 = blockIdx.x * (1 << tprsh) + (tid & ((1 << tprsh) - 1));
  int lo = indptr[d], hi = indptr[d + 1];
  float4 s = make_float4(0.f, 0.f, 0.f, 0.f);
  for (int j = lo; j < hi; j++) {
    float4 v = ((const float4*)(src + (size_t)idx[j] * D))[k4];
    s.x += v.x; s.y += v.y; s.z += v.z; s.w += v.w;
  }
  int c = hi - lo;
  float inv = 1.f / (float)(c > 0 ? c : 1);
  s.x *= inv; s.y *= inv; s.z *= inv; s.w *= inv;
  ushort4 h, l;
  h.x = f2bf(s.x); l.x = f2bf(s.x - bf2f(h.x));
  h.y = f2bf(s.y); l.y = f2bf(s.y - bf2f(h.y));
  h.z = f2bf(s.z); l.z = f2bf(s.z - bf2f(h.z));
  h.w = f2bf(s.w); l.w = f2bf(s.w - bf2f(h.w));
  ((ushort4*)(dh + (size_t)d * D))[k4] = h;
  ((ushort4*)(dl + (size_t)d * D))[k4] = l;
}

// ---------------- dual split-bf16 x3 MFMA NT GEMM, 256x256, in-kernel W cvt ----
// Grid 256: swz>>6 = q: product p=q>>1, K-half kh=q&1; P[q] = raw partial.
// fp32 (weight) side staged RAW to LDS (same bytes as h+l), cvtpk'd in-reg.
// bf16 (activation) side staged h+l. 8 waves, wave tile 128x64; BK=32.
// 2-buf ring, 2 barriers/tile, counted vmcnt(8) (8 GLDS/stage; r8-proven).
// Swizzles (both verified conflict-free, 2-way max):
//  fp32: 8 slots/row, physical p holds logical p^(r&7).
//  bf16: 4 slots/row, physical p holds logical p^((r>>1)&3).
#define GLDS(g, l)                                                             \
  __builtin_amdgcn_global_load_lds(                                            \
      (const __attribute__((address_space(1))) void*)(g),                      \
      (__attribute__((address_space(3))) void*)(l), 16, 0, 0)

#define BAR()                                                                  \
  {                                                                            \
    asm volatile("" ::: "memory");                                             \
    __builtin_amdgcn_s_barrier();                                              \
    asm volatile("" ::: "memory");                                             \
  }

template <int AF32>  // 1: fp32 side = A/M (col, W=[4096][4096]); 0: fp32 = B/N
__global__ __launch_bounds__(512, 1) void dual_gemm_kernel(
    const float* __restrict__ Wf1, const float* __restrict__ Wf2,
    const unsigned short* __restrict__ Xh1, const unsigned short* __restrict__ Xl1,
    const unsigned short* __restrict__ Xh2, const unsigned short* __restrict__ Xl2,
    float* __restrict__ P0, float* __restrict__ P1,
    float* __restrict__ P2, float* __restrict__ P3,
    int Ktot, int Kblk) {
  // per buf 64KB: [0,32K) fp32 256x32 f32; [32K,48K) h 256x32; [48K,64K) l.
  __shared__ __align__(16) char smraw[2][65536];
  const int tid = threadIdx.x; // 512
  const int lane = tid & 63;
  const int wid = tid >> 6;
  const int wm = wid >> 2, wn = wid & 3; // wave tile: rows wm*128.., cols wn*64..

  const int bid = blockIdx.x;                  // 256
  const int swz = (bid & 7) * 32 + (bid >> 3); // XCD-chunked
  const int q = swz >> 6;                      // 0..3
  const int p = q >> 1, kh = q & 1;
  const int tile = swz & 63;                   // 16 m x 4 n
  const int bm0 = (tile >> 2) * 256;
  const int bn0 = (tile & 3) * 256;
  const size_t kbase = (size_t)kh * Kblk;

  const float* Wf = p ? Wf2 : Wf1;
  const unsigned short* Xh = p ? Xh2 : Xh1;
  const unsigned short* Xl = p ? Xl2 : Xl1;
  const size_t wrow = AF32 ? (size_t)bm0 : (size_t)bn0; // fp32-side tile rows
  const size_t xrow = AF32 ? (size_t)bn0 : (size_t)bm0; // bf16-side tile rows

  // fp32 staging: 2048 16B-units; thread covers u=tid+512v (v=0..3): rows
  // fr+64v, slot tid&7 holds logical (tid&7)^(fr&7) (64v preserves &7).
  const int fr = tid >> 3;
  const int fq = (tid & 7) ^ (fr & 7);
  const float* gF = Wf + (wrow + fr) * Ktot + kbase + fq * 4;
  // bf16 staging: 1024 units per h/l; u=tid+512v (v=0..1): rows hr+128v.
  const int hr = tid >> 2;
  const int hq = (tid & 3) ^ ((hr >> 1) & 3);
  const unsigned short* gH = Xh + (xrow + hr) * Ktot + kbase + hq * 8;
  const unsigned short* gL = Xl + (xrow + hr) * Ktot + kbase + hq * 8;

  // exactly 8 GLDS per STAGE (vmcnt counting relies on it)
#define STAGE(buf)                                                             \
  {                                                                            \
    char* base = &smraw[buf][0];                                               \
    GLDS(gF, base + tid * 16);                                                 \
    GLDS(gF + (size_t)64 * Ktot, base + 8192 + tid * 16);                      \
    GLDS(gF + (size_t)128 * Ktot, base + 16384 + tid * 16);                    \
    GLDS(gF + (size_t)192 * Ktot, base + 24576 + tid * 16);                    \
    GLDS(gH, base + 32768 + tid * 16);                                         \
    GLDS(gH + (size_t)128 * Ktot, base + 40960 + tid * 16);                    \
    GLDS(gL, base + 49152 + tid * 16);                                         \
    GLDS(gL + (size_t)128 * Ktot, base + 57344 + tid * 16);                    \
    gF += 32; gH += 32; gL += 32;                                              \
  }

  // read offsets. s = lane>>4 (k-slice).
  const int s = lane >> 4;
  // fp32: frag row rf = FROW + f*16 + (lane&15); byte = rf*128 + offF{0,1}
  const int offF0 = ((2 * s) ^ (lane & 7)) * 16;
  const int offF1 = ((2 * s + 1) ^ (lane & 7)) * 16;
  const int FROW = (AF32 ? wm * 128 : wn * 64) + (lane & 15);
  // bf16: frag row rh = HROW + j*16 + (lane&15); byte = rh*64 + offH
  const int offH = (s ^ (((lane & 15) >> 1) & 3)) * 16;
  const int HROW = (AF32 ? wn * 64 : wm * 128) + (lane & 15);

  f32x4 acc[8][4];
#pragma unroll
  for (int i = 0; i < 8; i++)
#pragma unroll
    for (int j = 0; j < 4; j++) acc[i][j] = (f32x4)(0.f);

  const int nt = Kblk / 32; // col: 64, row: 16
  STAGE(0);
  STAGE(1);
  int cur = 0;
#pragma unroll 1
  for (int t = 0; t < nt; ++t) {
    if (t < nt - 1) {
      asm volatile("s_waitcnt vmcnt(8)" ::: "memory"); // tile t landed
    } else {
      asm volatile("s_waitcnt vmcnt(0)" ::: "memory");
    }
    BAR();
    const char* base = &smraw[cur][0];
    const char* baseH = base + 32768;
    const char* baseL = base + 49152;

    if constexpr (AF32) {
      // 8 fp32 M-frags (cvt), 4 bf16 N-frags
      short8 rdh[4], rdl[4], ch[4], cl[4];
#pragma unroll
      for (int j = 0; j < 4; j++) {
        int rh = HROW + j * 16;
        rdh[j] = *(const short8*)(baseH + rh * 64 + offH);
        rdl[j] = *(const short8*)(baseL + rh * 64 + offH);
      }
#pragma unroll
      for (int half = 0; half < 2; half++) {
#pragma unroll
        for (int f = 0; f < 4; f++) {
          int rf = FROW + (half * 4 + f) * 16;
          float4 a = *(const float4*)(base + rf * 128 + offF0);
          float4 b = *(const float4*)(base + rf * 128 + offF1);
          cvt_f4pair(a, b, ch[f], cl[f]);
        }
        __builtin_amdgcn_s_setprio(1);
#pragma unroll
        for (int f = 0; f < 4; f++)
#pragma unroll
          for (int j = 0; j < 4; j++)
            acc[half * 4 + f][j] = __builtin_amdgcn_mfma_f32_16x16x32_bf16(
                ch[f], rdh[j], acc[half * 4 + f][j], 0, 0, 0);
#pragma unroll
        for (int f = 0; f < 4; f++)
#pragma unroll
          for (int j = 0; j < 4; j++)
            acc[half * 4 + f][j] = __builtin_amdgcn_mfma_f32_16x16x32_bf16(
                ch[f], rdl[j], acc[half * 4 + f][j], 0, 0, 0);
#pragma unroll
        for (int f = 0; f < 4; f++)
#pragma unroll
          for (int j = 0; j < 4; j++)
            acc[half * 4 + f][j] = __builtin_amdgcn_mfma_f32_16x16x32_bf16(
                cl[f], rdh[j], acc[half * 4 + f][j], 0, 0, 0);
        __builtin_amdgcn_s_setprio(0);
      }
    } else {
      // 8 bf16 M-frags, 4 fp32 N-frags (cvt)
      short8 ch[4], cl[4];
#pragma unroll
      for (int f = 0; f < 4; f++) {
        int rf = FROW + f * 16;
        float4 a = *(const float4*)(base + rf * 128 + offF0);
        float4 b = *(const float4*)(base + rf * 128 + offF1);
        cvt_f4pair(a, b, ch[f], cl[f]);
      }
#pragma unroll
      for (int half = 0; half < 2; half++) {
        short8 rdh[4], rdl[4];
#pragma unroll
        for (int i = 0; i < 4; i++) {
          int rh = HROW + (half * 4 + i) * 16;
          rdh[i] = *(const short8*)(baseH + rh * 64 + offH);
          rdl[i] = *(const short8*)(baseL + rh * 64 + offH);
        }
        __builtin_amdgcn_s_setprio(1);
#pragma unroll
        for (int i = 0; i < 4; i++)
#pragma unroll
          for (int j = 0; j < 4; j++)
            acc[half * 4 + i][j] = __builtin_amdgcn_mfma_f32_16x16x32_bf16(
                rdh[i], ch[j], acc[half * 4 + i][j], 0, 0, 0);
#pragma unroll
        for (int i = 0; i < 4; i++)
#pragma unroll
          for (int j = 0; j < 4; j++)
            acc[half * 4 + i][j] = __builtin_amdgcn_mfma_f32_16x16x32_bf16(
                rdl[i], ch[j], acc[half * 4 + i][j], 0, 0, 0);
#pragma unroll
        for (int i = 0; i < 4; i++)
#pragma unroll
          for (int j = 0; j < 4; j++)
            acc[half * 4 + i][j] = __builtin_amdgcn_mfma_f32_16x16x32_bf16(
                rdh[i], cl[j], acc[half * 4 + i][j], 0, 0, 0);
        __builtin_amdgcn_s_setprio(0);
      }
    }
    BAR(); // all waves done reading buf cur
    if (t + 2 < nt) STAGE(cur);
    cur ^= 1;
  }

  float* P = q == 0 ? P0 : q == 1 ? P1 : q == 2 ? P2 : P3;
  const int rq = (lane >> 4) * 4;
  const int cq = lane & 15;
#pragma unroll
  for (int i = 0; i < 8; i++) {
#pragma unroll
    for (int j = 0; j < 4; j++) {
#pragma unroll
      for (int e = 0; e < 4; e++) {
        int row = bm0 + wm * 128 + i * 16 + rq + e;
        int col = bn0 + wn * 64 + j * 16 + cq;
        P[(size_t)row * 1024 + col] = acc[i][j][e];
      }
    }
  }
}

// ---------------- combine4: C = leaky(P0..P3 + bias[row]) + hi/lo split --------
__global__ void combine_split_kernel(const float* __restrict__ P0, const float* __restrict__ P1,
                                     const float* __restrict__ P2, const float* __restrict__ P3,
                                     const float* __restrict__ bias, float* __restrict__ Cf,
                                     unsigned short* __restrict__ Ch,
                                     unsigned short* __restrict__ Cl) {
  int i = blockIdx.x * 256 + threadIdx.x; // float4 index, 1M total
  float4 a = ((const float4*)P0)[i];
  float4 b = ((const float4*)P1)[i];
  float4 c = ((const float4*)P2)[i];
  float4 d = ((const float4*)P3)[i];
  float bb = bias[(i * 4) >> 10];
  float4 v;
  v.x = a.x + b.x + c.x + d.x + bb;
  v.y = a.y + b.y + c.y + d.y + bb;
  v.z = a.z + b.z + c.z + d.z + bb;
  v.w = a.w + b.w + c.w + d.w + bb;
  v.x = v.x > 0.f ? v.x : 0.01f * v.x;
  v.y = v.y > 0.f ? v.y : 0.01f * v.y;
  v.z = v.z > 0.f ? v.z : 0.01f * v.z;
  v.w = v.w > 0.f ? v.w : 0.01f * v.w;
  ((float4*)Cf)[i] = v;
  ushort4 h, l;
  h.x = f2bf(v.x); l.x = f2bf(v.x - bf2f(h.x));
  h.y = f2bf(v.y); l.y = f2bf(v.y - bf2f(h.y));
  h.z = f2bf(v.z); l.z = f2bf(v.z - bf2f(h.z));
  h.w = f2bf(v.w); l.w = f2bf(v.w - bf2f(h.w));
  ((ushort4*)Ch)[i] = h;
  ((ushort4*)Cl)[i] = l;
}

// ---------------- combine4: C = leaky(P0..P3 + bias[col]) ----------------
__global__ void combine_kernel(const float* __restrict__ P0, const float* __restrict__ P1,
                               const float* __restrict__ P2, const float* __restrict__ P3,
                               const float* __restrict__ bias, float* __restrict__ C) {
  int i = blockIdx.x * 256 + threadIdx.x;
  float4 a = ((const float4*)P0)[i];
  float4 b = ((const float4*)P1)[i];
  float4 c = ((const float4*)P2)[i];
  float4 d = ((const float4*)P3)[i];
  float4 bb = *(const float4*)(bias + ((i * 4) & 1023));
  float4 v;
  v.x = a.x + b.x + c.x + d.x + bb.x;
  v.y = a.y + b.y + c.y + d.y + bb.y;
  v.z = a.z + b.z + c.z + d.z + bb.z;
  v.w = a.w + b.w + c.w + d.w + bb.w;
  v.x = v.x > 0.f ? v.x : 0.01f * v.x;
  v.y = v.y > 0.f ? v.y : 0.01f * v.y;
  v.z = v.z > 0.f ? v.z : 0.01f * v.z;
  v.w = v.w > 0.f ? v.w : 0.01f * v.w;
  ((float4*)C)[i] = v;
}

extern "C" void kernel_launch(void* const* d_in, const int* in_sizes, int n_in,
                              void* d_out, int out_size, void* d_ws, size_t ws_size,
                              hipStream_t stream) {
  const float* x      = (const float*)d_in[0];
  const float* col_Wl = (const float*)d_in[1];
  const float* col_Wr = (const float*)d_in[2];
  const float* col_b  = (const float*)d_in[3];
  const float* row_Wl = (const float*)d_in[4];
  const float* row_Wr = (const float*)d_in[5];
  const float* row_b  = (const float*)d_in[6];
  const int*   knn    = (const int*)d_in[7];   // [2][KNN_E]
  const int*   genet  = (const int*)d_in[8];   // [2][GENET_E]
  float* out = (float*)d_out;

  const size_t MAT = (size_t)COL_DIM * ROW_DIM; // 4M elements
  const size_t WCOL = (size_t)COL_DIM * COL_DIM;
  const size_t WROW = (size_t)ROW_DIM * ROW_DIM;
  char* w = (char*)d_ws;
  float* X1f = (float*)w; w += MAT * 4;                   // ET then E1 (fp32)
  unsigned short* X2h = (unsigned short*)w; w += MAT * 2; // ETh/l then E1h/l
  unsigned short* X2l = (unsigned short*)w; w += MAT * 2;
  unsigned short* X3h = (unsigned short*)w; w += MAT * 2; // Mh/l then Gh/l
  unsigned short* X3l = (unsigned short*)w; w += MAT * 2;
  float* PP0 = (float*)w; w += MAT * 4;
  float* PP1 = (float*)w; w += MAT * 4;
  float* PP2 = (float*)w; w += MAT * 4;
  float* PP3 = (float*)w; w += MAT * 4;
  int* kcnt = (int*)w; w += 1024 * 4;
  int* kptr = (int*)w; w += 1025 * 4;
  int* kidx = (int*)w; w += KNN_E * 4;
  int* gcnt = (int*)w; w += 4096 * 4;
  int* gptr = (int*)w; w += 4097 * 4;
  int* gidx = (int*)w; w += (size_t)GENET_E * 4;

  // ---- CSR build (deterministic via per-bucket value sort) ----
  hipMemsetAsync(kcnt, 0, 1024 * 4, stream);
  hipMemsetAsync(gcnt, 0, 4096 * 4, stream);
  count_kernel<<<KNN_E / 256, 256, 0, stream>>>(knn + KNN_E, KNN_E, kcnt);
  count_kernel<<<GENET_E / 256, 256, 0, stream>>>(genet + GENET_E, GENET_E, gcnt);
  scan_kernel<<<1, 1024, 0, stream>>>(kcnt, kptr, 1024);
  scan_kernel<<<1, 1024, 0, stream>>>(gcnt, gptr, 4096);
  copy_int_kernel<<<4, 256, 0, stream>>>(kptr, kcnt, 1024);
  copy_int_kernel<<<16, 256, 0, stream>>>(gptr, gcnt, 4096);
  fill_kernel<<<KNN_E / 256, 256, 0, stream>>>(knn, knn + KNN_E, KNN_E, kcnt, kidx);
  fill_kernel<<<GENET_E / 256, 256, 0, stream>>>(genet, genet + GENET_E, GENET_E, gcnt, gidx);
  rank_sort_kernel<<<256, 256, 0, stream>>>(kptr, kidx, 1024);
  rank_sort_kernel<<<1024, 256, 0, stream>>>(gptr, gidx, 4096);

  const float* Ein = x;
  for (int i = 0; i < NUM_LAYERS; i++) {
    const float* cWl = col_Wl + (size_t)i * WCOL;
    const float* cWr = col_Wr + (size_t)i * WCOL;
    const float* cb  = col_b + (size_t)i * COL_DIM;
    const float* rWl = row_Wl + (size_t)i * WROW;
    const float* rWr = row_Wr + (size_t)i * WROW;
    const float* rb  = row_b + (size_t)i * ROW_DIM;

    // ---- column branch: E1 = leaky(cWl@M^T + cWr@ET^T + cb[row]) ----
    transpose_split_kernel<<<dim3(ROW_DIM / 32, COL_DIM / 32), dim3(32, 8), 0, stream>>>(
        Ein, X1f, X2h, X2l, COL_DIM, ROW_DIM);
    agg_slice_kernel<<<dim3(8, 512), 256, 0, stream>>>(X1f, X3h, X3l, kptr, kidx,
                                                       COL_DIM, 7);
    // p=0: cWl x M(knn mean); p=1: cWr x ET. fp32 = A/M side.
    dual_gemm_kernel<1><<<256, 512, 0, stream>>>(
        cWl, cWr, X3h, X3l, X2h, X2l,
        PP0, PP1, PP2, PP3, COL_DIM, COL_DIM / 2);
    combine_split_kernel<<<4096, 256, 0, stream>>>(PP0, PP1, PP2, PP3, cb,
                                                   X1f, X2h, X2l); // E1 f32+h/l
    // ---- row branch: out = leaky(G@rWl^T + E1@rWr^T + rb[col]) ----
    agg_slice_kernel<<<dim3(8, 512), 256, 0, stream>>>(X1f, X3h, X3l, gptr, gidx,
                                                       ROW_DIM, 5);
    // p=0: G x rWl; p=1: E1 x rWr. fp32 = B/N side.
    dual_gemm_kernel<0><<<256, 512, 0, stream>>>(
        rWl, rWr, X3h, X3l, X2h, X2l,
        PP0, PP1, PP2, PP3, ROW_DIM, ROW_DIM / 2);
    combine_kernel<<<4096, 256, 0, stream>>>(PP0, PP1, PP2, PP3, rb, out);

    Ein = out;
  }
}